// Round 1
// 307.338 us; speedup vs baseline: 1.0435x; 1.0435x over previous
//
#include <hip/hip_runtime.h>
#include <stdint.h>

namespace {
constexpr int kH = 4, kD = 32, kEF = 32, kNT = 4, kET = 8;
constexpr int kHD = kH * kD;  // 128
constexpr float kNegSlope = 0.2f;
constexpr int kNB = 782;   // coarse buckets: dst>>7, ceil(100000/128)
constexpr int kHB = 512;   // histogram/scatter blocks
constexpr int kXP = 20;    // transpose-LDS row stride in floats (80B: bank-phase rotation)

using f32x2 = __attribute__((ext_vector_type(2))) float;

__device__ __forceinline__ float lrelu(float x) { return x > 0.f ? x : kNegSlope * x; }

// ee table (block 0) + per-node el/er/fs(fp8 e4m3). No atomics.
// 32 lanes per node, float4 (16B) loads per lane.
__global__ void __launch_bounds__(256) k_init(
    const float* __restrict__ feat, const float* __restrict__ fc,
    const float* __restrict__ edge_emb, const float* __restrict__ W_e,
    const float* __restrict__ attn_l, const float* __restrict__ attn_r,
    const float* __restrict__ attn_e, const int* __restrict__ node_types,
    float* __restrict__ el, float* __restrict__ er, uint8_t* __restrict__ fs,
    float* __restrict__ ee_tab, int N) {
  if (blockIdx.x == 0 && threadIdx.x < kET * kH) {
    int et = threadIdx.x / kH, h = threadIdx.x % kH;
    float acc = 0.f;
    for (int f = 0; f < kEF; ++f) {
      const float* wrow = W_e + (h * kEF + f) * kEF;
      const float* erow = edge_emb + et * kEF;
      float emb = 0.f;
      for (int k = 0; k < kEF; ++k) emb += erow[k] * wrow[k];
      acc += emb * attn_e[h * kEF + f];
    }
    ee_tab[et * kH + h] = acc;
  }
  int gid = blockIdx.x * blockDim.x + threadIdx.x;
  int node = gid >> 5;
  int lane = threadIdx.x & 31;
  if (node >= N) return;
  int nt = node_types[node];
  float4 f4 = *(const float4*)(feat + (size_t)(node << 7) + lane * 4);
  float4 c4 = *(const float4*)(fc + nt * kHD + lane * 4);
  float4 al = *(const float4*)(attn_l + lane * 4);
  float4 ar = *(const float4*)(attn_r + lane * 4);
  float fx = f4.x * c4.x, fy = f4.y * c4.y, fz = f4.z * c4.z, fw = f4.w * c4.w;
  // pack this lane's 4 dims into one fp8x4 word: byte k == dim 4*lane+k
  int w = __builtin_amdgcn_cvt_pk_fp8_f32(fx, fy, 0, false);
  w = __builtin_amdgcn_cvt_pk_fp8_f32(fz, fw, w, true);
  *(int*)(fs + (size_t)(node << 7) + lane * 4) = w;
  float pl = fx * al.x + fy * al.y + fz * al.z + fw * al.w;
  float pr = fx * ar.x + fy * ar.y + fz * ar.z + fw * ar.w;
#pragma unroll
  for (int off = 1; off < 8; off <<= 1) {
    pl += __shfl_xor(pl, off);
    pr += __shfl_xor(pr, off);
  }
  if ((lane & 7) == 0) {
    int h = lane >> 3;
    el[node * kH + h] = pl;
    er[node * kH + h] = pr;
  }
}

// per-block privatized coarse histogram (LDS atomics only)
__global__ void __launch_bounds__(256) k_hist(const int* __restrict__ dst,
                                              int* __restrict__ partial, int E) {
  __shared__ int h[kNB];
  for (int i = threadIdx.x; i < kNB; i += 256) h[i] = 0;
  __syncthreads();
  int per = (E + gridDim.x - 1) / gridDim.x;
  int e0 = blockIdx.x * per;
  int e1 = min(e0 + per, E);
  for (int i = e0 + threadIdx.x; i < e1; i += 256) atomicAdd(&h[dst[i] >> 7], 1);
  __syncthreads();
  for (int i = threadIdx.x; i < kNB; i += 256) partial[blockIdx.x * kNB + i] = h[i];
}

// column scan: one block per bucket; partial[blk][b] -> exclusive over blk; btot[b]=sum
__global__ void __launch_bounds__(256) k_scanA(int* __restrict__ partial,
                                               int* __restrict__ btot) {
  __shared__ int bufa[kHB], bufb[kHB];
  int b = blockIdx.x, t = threadIdx.x;
  bufa[t] = partial[t * kNB + b];
  bufa[t + 256] = partial[(t + 256) * kNB + b];
  __syncthreads();
  int* cur = bufa;
  int* nxt = bufb;
  for (int off = 1; off < kHB; off <<= 1) {
    for (int i = t; i < kHB; i += 256) nxt[i] = cur[i] + (i >= off ? cur[i - off] : 0);
    __syncthreads();
    int* sw = cur; cur = nxt; nxt = sw;
  }
  partial[t * kNB + b] = t ? cur[t - 1] : 0;
  partial[(t + 256) * kNB + b] = cur[t + 255];
  if (t == 0) btot[b] = cur[kHB - 1];
}

// bucket base scan (single block)
__global__ void __launch_bounds__(1024) k_scanB(const int* __restrict__ btot,
                                                int* __restrict__ bbase) {
  __shared__ int bufa[1024], bufb[1024];
  int t = threadIdx.x;
  bufa[t] = (t < kNB) ? btot[t] : 0;
  __syncthreads();
  int* cur = bufa;
  int* nxt = bufb;
  for (int off = 1; off < 1024; off <<= 1) {
    nxt[t] = cur[t] + (t >= off ? cur[t - off] : 0);
    __syncthreads();
    int* sw = cur; cur = nxt; nxt = sw;
  }
  if (t < kNB) bbase[t] = t ? cur[t - 1] : 0;
  if (t == kNB - 1) bbase[kNB] = cur[t];
}

// scatter into coarse buckets; deterministic positions, LDS-atomic local ranks
__global__ void __launch_bounds__(256) k_scatter2(
    const int* __restrict__ dst, const int* __restrict__ src,
    const int* __restrict__ e_feat, const int* __restrict__ partial,
    const int* __restrict__ bbase, int* __restrict__ tmp, int E) {
  __shared__ int h[kNB];
  for (int i = threadIdx.x; i < kNB; i += 256) h[i] = 0;
  __syncthreads();
  int per = (E + gridDim.x - 1) / gridDim.x;
  int e0 = blockIdx.x * per;
  int e1 = min(e0 + per, E);
  const int* myrow = partial + blockIdx.x * kNB;
  for (int i = e0 + threadIdx.x; i < e1; i += 256) {
    int d = dst[i];
    int b = d >> 7;
    int lr = atomicAdd(&h[b], 1);
    int pos = bbase[b] + myrow[b] + lr;
    tmp[pos] = src[i] | (e_feat[i] << 17) | ((d & 127) << 20);
  }
}

// per-bucket fine sort: write ptr + dst-sorted csr (bucket-local writes)
__global__ void __launch_bounds__(256) k_build(const int* __restrict__ bbase,
                                               const int* __restrict__ tmp,
                                               int* __restrict__ ptr,
                                               int* __restrict__ csr, int N, int E) {
  __shared__ int fh[128], fb[128], sc[128];
  int b = blockIdx.x, t = threadIdx.x;
  int s0 = bbase[b], s1 = bbase[b + 1];
  if (t < 128) fh[t] = 0;
  __syncthreads();
  for (int j = s0 + t; j < s1; j += 256) atomicAdd(&fh[tmp[j] >> 20], 1);
  __syncthreads();
  if (t < 128) sc[t] = fh[t];
  __syncthreads();
  for (int off = 1; off < 128; off <<= 1) {
    int v = 0;
    if (t < 128 && t >= off) v = sc[t - off];
    __syncthreads();
    if (t < 128) sc[t] += v;
    __syncthreads();
  }
  if (t < 128) {
    fb[t] = sc[t] - fh[t];  // exclusive
    int d = (b << 7) + t;
    if (d < N) ptr[d] = s0 + fb[t];
    fh[t] = 0;
  }
  if (b == gridDim.x - 1 && t == 0) ptr[N] = E;
  __syncthreads();
  for (int j = s0 + t; j < s1; j += 256) {
    int v = tmp[j];
    int dl = v >> 20;
    int r = atomicAdd(&fh[dl], 1);
    csr[s0 + fb[dl] + r] = v & 0xFFFFF;  // src | et<<17
  }
}

// one wave per dst node, 8 edges x 8 lanes (16 dims / lane, fp8 rows).
// 2-deep software pipeline: el/fs gathers for edge-slot i+1 issue during compute
// of slot i; csr prefetched 2 slots ahead. Epilogue: LDS transpose (4 ds_write_b128
// + 8 ds_read_b64 per lane) instead of 48 shuffles; coalesced 64-lane float2 store.
__global__ void __launch_bounds__(256) k_fused(
    const uint8_t* __restrict__ fs, const float* __restrict__ feat,
    const float* __restrict__ el, const float* __restrict__ er,
    const float* __restrict__ ee_tab, const int* __restrict__ ptr,
    const int* __restrict__ csr, float* __restrict__ rst,
    float* __restrict__ rinv_buf, int N) {
  __shared__ float ee_sh[kET * kH];
  __shared__ __align__(16) float xp[4][64 * kXP];
  if (threadIdx.x < kET * kH) ee_sh[threadIdx.x] = ee_tab[threadIdx.x];
  __syncthreads();
  int lane = threadIdx.x & 63;
  int wid = threadIdx.x >> 6;
  int node = blockIdx.x * 4 + wid;
  bool nvalid = node < N;
  int nodec = nvalid ? node : 0;
  int start = 0, end = 0;
  if (nvalid) {
    start = ptr[node];
    end = ptr[node + 1];
  }

  int g = lane >> 3;   // edge slot (8 edges in flight)
  int q = lane & 7;    // dim-lane: dims [q*16, q*16+16)
  int head = q >> 1;
  int qoff = q << 4;
  float er_h = er[nodec * kH + head];

  float sm = 0.f;
  f32x2 acc[8];
#pragma unroll
  for (int k = 0; k < 8; ++k) acc[k] = (f32x2){0.f, 0.f};

  int j = start + g;
  // prologue: stage 0 fully in flight, stage 1 csr word in flight
  int pk0 = csr[(j < end) ? j : 0];
  int s0 = pk0 & 0x1FFFF;
  float elv0 = el[(s0 << 2) + head];
  int4 w0 = *(const int4*)(fs + (size_t)(s0 << 7) + qoff);
  float ee0 = ee_sh[((pk0 >> 17) << 2) + head];
  int pk1 = csr[(j + 8 < end) ? j + 8 : 0];

  while (j < end) {
    // issue gathers for stage i+1 (pk1 already resident)
    int s1 = pk1 & 0x1FFFF;
    float elv1 = el[(s1 << 2) + head];
    int4 w1 = *(const int4*)(fs + (size_t)(s1 << 7) + qoff);
    float ee1 = ee_sh[((pk1 >> 17) << 2) + head];
    // issue csr word for stage i+2
    int pk2 = csr[(j + 16 < end) ? j + 16 : 0];
    // compute stage i (data issued one full iteration ago)
    float ex = __expf(lrelu(elv0 + er_h + ee0));
    sm += ex;
    f32x2 ex2 = {ex, ex};
#pragma unroll
    for (int c = 0; c < 4; ++c) {
      int wc = c == 0 ? w0.x : c == 1 ? w0.y : c == 2 ? w0.z : w0.w;
      acc[2 * c + 0] += ex2 * __builtin_amdgcn_cvt_pk_f32_fp8(wc, false);
      acc[2 * c + 1] += ex2 * __builtin_amdgcn_cvt_pk_f32_fp8(wc, true);
    }
    elv0 = elv1;
    w0 = w1;
    ee0 = ee1;
    pk1 = pk2;
    j += 8;
  }

  // per-head softmax denominator: reduce over the 8 edge slots (q preserved)
  sm += __shfl_xor(sm, 8);
  sm += __shfl_xor(sm, 16);
  sm += __shfl_xor(sm, 32);
  float rinv = sm > 0.f ? 1.f / sm : 0.f;

  // LDS transpose: row = lane (80B stride -> write bank-phase rotates, conflict-free)
  float* row = &xp[wid][lane * kXP];
#pragma unroll
  for (int c = 0; c < 4; ++c) {
    float4 v4 = {acc[2 * c].x, acc[2 * c].y, acc[2 * c + 1].x, acc[2 * c + 1].y};
    *(float4*)(row + c * 4) = v4;
  }
  __syncthreads();
  // lane L sums dims (2L, 2L+1) over the 8 edge-slot rows
  int qsrc = lane >> 3;
  int coff = (lane & 7) * 2;
  const float* base = &xp[wid][qsrc * kXP + coff];
  f32x2 v = {0.f, 0.f};
#pragma unroll
  for (int gg = 0; gg < 8; ++gg) v += *(const f32x2*)(base + gg * 8 * kXP);

  float rs = __shfl(rinv, (lane >> 4) << 1);     // rinv for head = lane>>4
  float rb = __shfl(rinv, lane << 1);            // rinv for head = lane (lanes 0..3)
  f32x2 f2 = *(const f32x2*)(feat + (size_t)(nodec << 7) + lane * 2);
  f32x2 o = v * rs + f2;
  if (nvalid) {
    *(f32x2*)(rst + (size_t)(node << 7) + lane * 2) = o;
    if (lane < kH) rinv_buf[node * kH + lane] = rb;
  }
}

// edge-parallel a computation in ORIGINAL edge order: coalesced float4 stores
__global__ void k_post(const int* __restrict__ src, const int* __restrict__ dst,
                       const int* __restrict__ e_feat, const float* __restrict__ el,
                       const float* __restrict__ er, const float* __restrict__ ee_tab,
                       const float* __restrict__ rinv_buf, float* __restrict__ out_a,
                       int E) {
  int i = blockIdx.x * blockDim.x + threadIdx.x;
  if (i >= E) return;
  int s = src[i], d = dst[i], et = e_feat[i];
  float4 elv = *(const float4*)(el + s * kH);
  float4 erv = *(const float4*)(er + d * kH);
  float4 ee = *(const float4*)(ee_tab + et * kH);
  float4 rv = *(const float4*)(rinv_buf + d * kH);
  float4 a;
  a.x = __expf(lrelu(elv.x + erv.x + ee.x)) * rv.x;
  a.y = __expf(lrelu(elv.y + erv.y + ee.y)) * rv.y;
  a.z = __expf(lrelu(elv.z + erv.z + ee.z)) * rv.z;
  a.w = __expf(lrelu(elv.w + erv.w + ee.w)) * rv.w;
  *(float4*)(out_a + (size_t)i * kH) = a;
}

}  // namespace

extern "C" void kernel_launch(void* const* d_in, const int* in_sizes, int n_in,
                              void* d_out, int out_size, void* d_ws, size_t ws_size,
                              hipStream_t stream) {
  const float* feat = (const float*)d_in[0];
  const float* fc = (const float*)d_in[1];
  const float* edge_emb = (const float*)d_in[2];
  const float* W_e = (const float*)d_in[3];
  const float* attn_l = (const float*)d_in[4];
  const float* attn_r = (const float*)d_in[5];
  const float* attn_e = (const float*)d_in[6];
  const int* node_types = (const int*)d_in[7];
  const int* e_feat = (const int*)d_in[8];
  const int* src = (const int*)d_in[9];
  const int* dst = (const int*)d_in[10];
  int N = in_sizes[7];
  int E = in_sizes[8];

  char* ws = (char*)d_ws;
  size_t off = 0;
  auto alloc = [&](size_t bytes) -> void* {
    void* p = ws + off;
    off = (off + bytes + 255) & ~(size_t)255;
    return p;
  };
  float* ee_tab = (float*)alloc((size_t)kET * kH * sizeof(float));
  float* el = (float*)alloc((size_t)N * kH * sizeof(float));
  float* er = (float*)alloc((size_t)N * kH * sizeof(float));
  float* rinv_buf = (float*)alloc((size_t)N * kH * sizeof(float));
  uint8_t* fs = (uint8_t*)alloc((size_t)N * kHD * sizeof(uint8_t));
  int* partial = (int*)alloc((size_t)kHB * kNB * sizeof(int));
  int* btot = (int*)alloc((size_t)kNB * sizeof(int));
  int* bbase = (int*)alloc((size_t)(kNB + 1) * sizeof(int));
  int* ptr = (int*)alloc((size_t)(N + 1) * sizeof(int));
  int* tmp = (int*)alloc((size_t)E * sizeof(int));
  int* csr = (int*)alloc((size_t)E * sizeof(int));

  k_init<<<(N + 7) / 8, 256, 0, stream>>>(feat, fc, edge_emb, W_e, attn_l, attn_r,
                                          attn_e, node_types, el, er, fs, ee_tab, N);
  k_hist<<<kHB, 256, 0, stream>>>(dst, partial, E);
  k_scanA<<<kNB, 256, 0, stream>>>(partial, btot);
  k_scanB<<<1, 1024, 0, stream>>>(btot, bbase);
  k_scatter2<<<kHB, 256, 0, stream>>>(dst, src, e_feat, partial, bbase, tmp, E);
  k_build<<<kNB, 256, 0, stream>>>(bbase, tmp, ptr, csr, N, E);

  float* rst = (float*)d_out;
  float* out_a = (float*)d_out + (size_t)N * kHD;
  k_fused<<<(N + 3) / 4, 256, 0, stream>>>(fs, feat, el, er, ee_tab, ptr, csr, rst,
                                           rinv_buf, N);
  k_post<<<(E + 255) / 256, 256, 0, stream>>>(src, dst, e_feat, el, er, ee_tab,
                                              rinv_buf, out_a, E);
}